// Round 12
// baseline (269.145 us; speedup 1.0000x reference)
//
#include <hip/hip_runtime.h>

typedef __attribute__((ext_vector_type(8))) _Float16 half8;
typedef __attribute__((ext_vector_type(4))) _Float16 half4;
typedef __attribute__((ext_vector_type(4))) float f32x4;

#define MFMA_K32(a, b, c) __builtin_amdgcn_mfma_f32_16x16x32_f16((a), (b), (c), 0, 0, 0)
#define MFMA_K16(a, b, c) __builtin_amdgcn_mfma_f32_16x16x16f16((a), (b), (c), 0, 0, 0)

// async global->LDS, 16B per lane; LDS dest = wave-uniform base + lane*16
__device__ inline void async16(const _Float16* g, _Float16* l) {
    __builtin_amdgcn_global_load_lds(
        (const __attribute__((address_space(1))) void*)g,
        (__attribute__((address_space(3))) void*)l, 16, 0, 0);
}

// ---------------------------------------------------------------------------
// B=32, S=512, Dm=768, H=12, d=64, M=16384.
// probs = (s*0.125+5)^2; probs /= (rowsum+1e-10); probs *= mask; ctx = probs@V
// Folded: ctx = (sum_k w_k * (mask_k v_k)) / (sum_k w_k + 1e-10)
// Q is pre-scaled by 0.125 at the GEMM epilogue, so attn uses s = q.k + 5.
// ---------------------------------------------------------------------------

// Kernel 0: fused prep — X f32->f16 cast (blocks 0..6143) and weight
// transpose+cast (blocks 6144..7871).
__global__ __launch_bounds__(256) void prep_kernel(
    const float* __restrict__ X, _Float16* __restrict__ Xh,
    const float* __restrict__ W0, const float* __restrict__ W1,
    const float* __restrict__ W2,
    _Float16* __restrict__ T0, _Float16* __restrict__ T1,
    _Float16* __restrict__ T2)
{
    __shared__ float tile[32][33];
    int bid = blockIdx.x;
    if (bid < 6144) {
        size_t idx = ((size_t)bid * 256 + threadIdx.x) * 8;
        float4 a = *(const float4*)(X + idx);
        float4 c = *(const float4*)(X + idx + 4);
        half8 hv;
        hv[0] = (_Float16)a.x; hv[1] = (_Float16)a.y;
        hv[2] = (_Float16)a.z; hv[3] = (_Float16)a.w;
        hv[4] = (_Float16)c.x; hv[5] = (_Float16)c.y;
        hv[6] = (_Float16)c.z; hv[7] = (_Float16)c.w;
        *(half8*)(Xh + idx) = hv;
    } else {
        int id = bid - 6144;                 // 1728 = 3 x 24 x 24
        int z = id / 576; id -= z * 576;
        int n0 = (id / 24) * 32, k0 = (id % 24) * 32;
        const float* W = (z == 0) ? W0 : (z == 1) ? W1 : W2;
        _Float16* T = (z == 0) ? T0 : (z == 1) ? T1 : T2;
        int tx = threadIdx.x & 31, ty = threadIdx.x >> 5;
#pragma unroll
        for (int r = 0; r < 4; ++r)
            tile[ty + 8 * r][tx] = W[(size_t)(k0 + ty + 8 * r) * 768 + n0 + tx];
        __syncthreads();
#pragma unroll
        for (int r = 0; r < 4; ++r)
            T[(size_t)(n0 + ty + 8 * r) * 768 + k0 + tx] =
                (_Float16)tile[tx][ty + 8 * r];
    }
}

// ---------------------------------------------------------------------------
// Kernel 2: fused QKV GEMM, C[16384 x 2304] over z = n/768.
// 128x128 tile, 256 thr, BK=64, counted-vmcnt double buffer — round-9 exact
// (best measured: 90.2-91.4 µs, VALUBusy 14%, conflicts 0).  Schedule work
// on this structure is CLOSED (~2050 cyc/iter structural wall at K=768).
// XOR swizzle: LDS chunk j of row r holds global chunk j^(r&7); readers use
// slot = ((ks<<2)+quad) ^ (row&7) -> 2-way (free).
// Epilogue: operand-role swap for z<2 computes C^T so reg r packs over d ->
// half4 stores.  Q pre-scaled 0.125; V^T [B,H,64,S] premasked.
// ---------------------------------------------------------------------------
__global__ __launch_bounds__(256) void qkv_gemm(
    const _Float16* __restrict__ Xh,
    const _Float16* __restrict__ W0, const _Float16* __restrict__ W1,
    const _Float16* __restrict__ W2,
    const float* __restrict__ b0, const float* __restrict__ b1,
    const float* __restrict__ b2,
    const float* __restrict__ mask,
    _Float16* __restrict__ Qo, _Float16* __restrict__ Ko,
    _Float16* __restrict__ Vo)
{
    int z = blockIdx.y / 6;
    int n0 = (blockIdx.y % 6) * 128;
    int m0 = blockIdx.x * 128;
    const _Float16* Wt = (z == 0) ? W0 : (z == 1) ? W1 : W2;
    const float* bias = (z == 0) ? b0 : (z == 1) ? b1 : b2;

    __shared__ __attribute__((aligned(16))) _Float16 As[2 * 8192];  // 32 KB
    __shared__ __attribute__((aligned(16))) _Float16 Bs[2 * 8192];  // 32 KB

    int t = threadIdx.x;
    int wave = t >> 6, lane = t & 63, quad = lane >> 4, l16 = lane & 15;
    int wm = (wave & 1) * 64, wn = (wave >> 1) * 64;

    // staging: chunk index c = slot*256 + t; row = c>>3, LDS slot j = c&7,
    // global chunk g = j ^ (row&7).  (slot*256 doesn't change row&7 or j.)
    int srow = t >> 3;               // 0..31 (row advances +32 per slot)
    int sg = (t & 7) ^ (srow & 7);   // global chunk this thread fetches

    const _Float16* gA = Xh + (size_t)(m0 + srow) * 768 + sg * 8;
    const _Float16* gB = Wt + (size_t)(n0 + srow) * 768 + sg * 8;
    _Float16* lA = As + t * 8;
    _Float16* lB = Bs + t * 8;

#define STAGE(buf, k0v) do {                                                   \
        async16(gA + (k0v),                        lA + (buf) * 8192);         \
        async16(gA + (size_t)1 * 32 * 768 + (k0v), lA + (buf) * 8192 + 2048);  \
        async16(gA + (size_t)2 * 32 * 768 + (k0v), lA + (buf) * 8192 + 4096);  \
        async16(gA + (size_t)3 * 32 * 768 + (k0v), lA + (buf) * 8192 + 6144);  \
        async16(gB + (k0v),                        lB + (buf) * 8192);         \
        async16(gB + (size_t)1 * 32 * 768 + (k0v), lB + (buf) * 8192 + 2048);  \
        async16(gB + (size_t)2 * 32 * 768 + (k0v), lB + (buf) * 8192 + 4096);  \
        async16(gB + (size_t)3 * 32 * 768 + (k0v), lB + (buf) * 8192 + 6144); } while (0)

    // operand-role swap: for z<2, C rows = W-dim (so r packs over d at the
    // store); for z==2 keep C rows = token (V wants [d][token] with r=token).
    const _Float16* Pa = (z == 2) ? As : Bs;   // feeds af (C rows)
    const _Float16* Pb = (z == 2) ? Bs : As;   // feeds bf (C cols)

    f32x4 acc[4][4] = {};

    // prologue: tile 0 -> buf 0 (8 loads in flight; first body wait covers)
    STAGE(0, 0);

    for (int kt = 0; kt < 12; ++kt) {
        int c = kt & 1;
        if (kt < 11) {
            STAGE(c ^ 1, (kt + 1) * 64);
            // counted wait: only the PREVIOUS iteration's 8 loads (issued a
            // full iteration ago) must have landed; the fresh 8 stay in flight
            asm volatile("s_waitcnt vmcnt(8)" ::: "memory");
        } else {
            asm volatile("s_waitcnt vmcnt(0)" ::: "memory");
        }
        __builtin_amdgcn_s_barrier();
        __builtin_amdgcn_sched_barrier(0);   // pin ds_reads below the barrier

        const _Float16* Pa_ = Pa + c * 8192;
        const _Float16* Pb_ = Pb + c * 8192;
#pragma unroll
        for (int ks = 0; ks < 2; ++ks) {
            half8 af[4], bf[4];
#pragma unroll
            for (int i = 0; i < 4; ++i) {
                int row = wm + i * 16 + l16;
                af[i] = *(const half8*)&Pa_[row * 64 +
                                            (((ks << 2) + quad) ^ (row & 7)) * 8];
            }
#pragma unroll
            for (int j = 0; j < 4; ++j) {
                int row = wn + j * 16 + l16;
                bf[j] = *(const half8*)&Pb_[row * 64 +
                                            (((ks << 2) + quad) ^ (row & 7)) * 8];
            }
#pragma unroll
            for (int i = 0; i < 4; ++i)
#pragma unroll
                for (int j = 0; j < 4; ++j)
                    acc[i][j] = MFMA_K32(af[i], bf[j], acc[i][j]);
        }
        __builtin_amdgcn_sched_barrier(0);   // pin ds_reads above the barrier
        __builtin_amdgcn_s_barrier();        // readers done before buf reuse
    }
#undef STAGE

    if (z != 2) {
        // C^T: row = n-dim = n0 + wm + i*16 + quad*4 + r (4 consecutive d,
        // head-aligned since quad*4+r < 16); col = token = m0 + wn + j*16 + l16.
#pragma unroll
        for (int i = 0; i < 4; ++i) {
            int nbase = n0 + wm + i * 16 + quad * 4;
            int hh = nbase >> 6, dbase = nbase & 63;
            float4 bv4 = *(const float4*)&bias[nbase];
#pragma unroll
            for (int j = 0; j < 4; ++j) {
                int token = m0 + wn + j * 16 + l16;
                int bb = token >> 9, s = token & 511;
                half4 pk;
                if (z == 0) {
#pragma unroll
                    for (int r = 0; r < 4; ++r)
                        pk[r] = (_Float16)((acc[i][j][r] + ((const float*)&bv4)[r]) * 0.125f);
                } else {
#pragma unroll
                    for (int r = 0; r < 4; ++r)
                        pk[r] = (_Float16)(acc[i][j][r] + ((const float*)&bv4)[r]);
                }
                size_t off = (((size_t)(bb * 12 + hh)) * 512 + s) * 64 + dbase;
                if (z == 0) *(half4*)&Qo[off] = pk;
                else        *(half4*)&Ko[off] = pk;
            }
        }
    } else {
        // V (unswapped): row = token = m0+wm+i*16+quad*4+r, col = n0+wn+j*16+l16
        float mk[4][4];
#pragma unroll
        for (int i = 0; i < 4; ++i) {
            int mbase = m0 + wm + i * 16 + quad * 4;
            int bb = mbase >> 9, s = mbase & 511;
#pragma unroll
            for (int r = 0; r < 4; ++r)
                mk[i][r] = mask[(size_t)bb * 512 + s + r];
        }
#pragma unroll
        for (int j = 0; j < 4; ++j) {
            int n = n0 + wn + j * 16 + l16;
            float bv = bias[n];
            int hh = n >> 6, d = n & 63;
#pragma unroll
            for (int i = 0; i < 4; ++i) {
                int mbase = m0 + wm + i * 16 + quad * 4;
                int bb = mbase >> 9, s = mbase & 511;
                // V^T [B,H,64,S], premasked; regs = consecutive tokens -> 8B store
                half4 pk;
#pragma unroll
                for (int r = 0; r < 4; ++r)
                    pk[r] = (_Float16)((acc[i][j][r] + bv) * mk[i][r]);
                size_t off = (((size_t)(bb * 12 + hh)) * 64 + d) * 512 + s;
                *(half4*)&Vo[off] = pk;
            }
        }
    }
}

// ---------------------------------------------------------------------------
// Kernel 3: power-law attention — BARRIER-FREE, LDS-FREE, 1 wave per block.
// Rationale (round-11 analysis): attn ≈ 85 µs vs 27 µs BW floor, and five
// LDS-staging/barrier variants all landed within ±10% — the invariant cost
// is the staging+sync structure itself.  K/V total is 49 MB (L3-resident),
// and the MFMA fragment layouts (K as A-op [key][d], V^T as B-op [d][key])
// EXACTLY match global memory layout — so load fragments straight from
// global, per kb-step, fully unrolled, zero barriers, zero LDS.
// Grid 3072 = 8 q-tiles x 384 bh, 64 thr (1 wave).  Sibling q-tiles of one
// (b,h) are ids {bh + 384*qb} ≡ bh mod 8 -> SAME XCD; they walk kt in
// lockstep so the instantaneous K/V window (16 KB x 48 bh = 768 KB) fits
// L2 -> first toucher fetches from L3/HBM, 7 siblings hit L2.
// 12 independent waves/CU free-run (VGPR-bound ~3/SIMD) -> TLP hides load
// latency with no sync points at all.
// Math unchanged: S^T = K Q^T via 16x16x32 (lane holds P[q=l16][k=quad*4+r]
// == A-frag of 16x16x16); rowsum via MFMA with ones; ctx += P@V via
// 16x16x16.  V premasked; rowsum over unmasked w == reference semantics.
// ---------------------------------------------------------------------------
__global__ __launch_bounds__(64) void attn_kernel(
    const _Float16* __restrict__ Q, const _Float16* __restrict__ K,
    const _Float16* __restrict__ Vt, float* __restrict__ out)
{
    int lane = threadIdx.x;
    int quad = lane >> 4, l16 = lane & 15;
    int wid = blockIdx.x;
    int bh = wid % 384;                    // = b*12 + h (tensor layout order)
    int qbase = (wid / 384) * 64;          // sibling waves same XCD (384%8==0)
    int b = bh / 12, h = bh - (bh / 12) * 12;

    const _Float16* Qp = Q + (size_t)bh * (512 * 64);
    const _Float16* Kp = K + (size_t)bh * (512 * 64);
    const _Float16* Vp = Vt + (size_t)bh * (64 * 512);

    // Q fragments (B-operand layout == row-major half8 at [query][d])
    half8 qf[4][2];
#pragma unroll
    for (int i = 0; i < 4; ++i)
#pragma unroll
        for (int ks = 0; ks < 2; ++ks)
            qf[i][ks] = *(const half8*)(Qp + (size_t)(qbase + i * 16 + l16) * 64 +
                                        ks * 32 + quad * 8);

    f32x4 ctx[4][4] = {};
    f32x4 rsum[4] = {};
    const half4 ones = {(_Float16)1.f, (_Float16)1.f, (_Float16)1.f, (_Float16)1.f};

    // fragment base pointers (add krow offsets per step)
    const _Float16* kg = Kp + (size_t)l16 * 64 + quad * 8;   // + krow*64 (+32 for kf1)
    const _Float16* vg = Vp + (size_t)l16 * 512 + quad * 4;  // + n*16*512 + krow

#pragma unroll
    for (int kt = 0; kt < 8; ++kt) {
#pragma unroll
        for (int kb = 0; kb < 4; ++kb) {
            int krow = kt * 64 + kb * 16;
            // A-fragments of K: 16 rows x 128B = global layout directly
            half8 kf0 = *(const half8*)(kg + (size_t)krow * 64);
            half8 kf1 = *(const half8*)(kg + (size_t)krow * 64 + 32);
            // B-fragments of V^T: [d][key], half4 at (n*16+l16, krow+quad*4)
            half4 vf[4];
#pragma unroll
            for (int n = 0; n < 4; ++n)
                vf[n] = *(const half4*)(vg + (size_t)(n * 16) * 512 + krow);

            // QK^T (independent chains over i)
            f32x4 sc[4];
#pragma unroll
            for (int i = 0; i < 4; ++i) {
                f32x4 s0 = {0.f, 0.f, 0.f, 0.f};
                s0 = MFMA_K32(kf0, qf[i][0], s0);
                sc[i] = MFMA_K32(kf1, qf[i][1], s0);
            }
            // w = (s+5)^2  (Q pre-scaled by 0.125)
            half4 pA[4];
#pragma unroll
            for (int i = 0; i < 4; ++i) {
#pragma unroll
                for (int r = 0; r < 4; ++r) {
                    float s = sc[i][r] + 5.0f;
                    pA[i][r] = (_Float16)(s * s);
                }
            }
            // rowsum
#pragma unroll
            for (int i = 0; i < 4; ++i)
                rsum[i] = MFMA_K16(pA[i], ones, rsum[i]);
            // PV
#pragma unroll
            for (int n = 0; n < 4; ++n)
#pragma unroll
                for (int i = 0; i < 4; ++i)
                    ctx[i][n] = MFMA_K16(pA[i], vf[n], ctx[i][n]);
        }
    }

    // epilogue: rsum reg r and ctx reg r both live on C row = quad*4+r
#pragma unroll
    for (int i = 0; i < 4; ++i) {
        f32x4 inv;
#pragma unroll
        for (int r = 0; r < 4; ++r)
            inv[r] = 1.0f / (rsum[i][r] + 1e-10f);
#pragma unroll
        for (int n = 0; n < 4; ++n)
#pragma unroll
            for (int r = 0; r < 4; ++r) {
                int q = qbase + i * 16 + quad * 4 + r;
                int d = n * 16 + l16;
                out[((size_t)b * 512 + q) * 768 + h * 64 + d] =
                    ctx[i][n][r] * inv[r];
            }
    }
}

// ---------------------------------------------------------------------------
extern "C" void kernel_launch(void* const* d_in, const int* in_sizes, int n_in,
                              void* d_out, int out_size, void* d_ws, size_t ws_size,
                              hipStream_t stream)
{
    const float* hs   = (const float*)d_in[0];
    const float* mask = (const float*)d_in[1];
    const float* Wq   = (const float*)d_in[2];
    const float* bq   = (const float*)d_in[3];
    const float* Wk   = (const float*)d_in[4];
    const float* bk   = (const float*)d_in[5];
    const float* Wv   = (const float*)d_in[6];
    const float* bv   = (const float*)d_in[7];
    float* out = (float*)d_out;

    char* ws = (char*)d_ws;
    _Float16* Wtq = (_Float16*)ws;            // 3 x 768*768 halves
    _Float16* Wtk = Wtq + 768 * 768;
    _Float16* Wtv = Wtk + 768 * 768;
    _Float16* Qb  = Wtv + 768 * 768;          // 3 x 16384*768 halves
    _Float16* Kb  = Qb + 16384 * 768;
    _Float16* Vb  = Kb + 16384 * 768;
    // ws use ~79 MB. Xh scratch lives in d_out (Xh 25 MB, dead before attn).
    _Float16* Xh = (_Float16*)d_out;

    prep_kernel<<<dim3(7872), 256, 0, stream>>>(hs, Xh, Wq, Wk, Wv,
                                                Wtq, Wtk, Wtv);
    qkv_gemm<<<dim3(128, 18), 256, 0, stream>>>(Xh, Wtq, Wtk, Wtv,
                                                bq, bk, bv, mask, Qb, Kb, Vb);
    attn_kernel<<<dim3(3072), 64, 0, stream>>>(Qb, Kb, Vb, out);
}